// Round 8
// baseline (523.243 us; speedup 1.0000x reference)
//
#include <hip/hip_runtime.h>
#include <hip/hip_bf16.h>
#include <math.h>

typedef short bf16x8 __attribute__((ext_vector_type(8)));
typedef _Float16 half8 __attribute__((ext_vector_type(8)));
typedef float f32x4 __attribute__((ext_vector_type(4)));

#define B_   128
#define T_   800
#define E_   100
#define HC   192       // 2H
#define OUTV 102400    // B*C*O

__device__ inline float squash_scale(float n2) {
    return (n2 / (n2 + 1.f)) * rsqrtf(fmaxf(n2, 1e-30f));
}

__device__ inline unsigned short bf16_bits(float x) {
    __hip_bfloat16 h = __float2bfloat16(x);
    return *(unsigned short*)&h;
}

__device__ inline unsigned int pack_bf16x2(float a, float b) {
    return (unsigned int)bf16_bits(a) | ((unsigned int)bf16_bits(b) << 16);
}

__device__ inline void split_hilo(float x, unsigned short& hi, unsigned short& lo) {
    __hip_bfloat16 h = __float2bfloat16(x);
    float hf = __bfloat162float(h);
    hi = *(unsigned short*)&h;
    __hip_bfloat16 l = __float2bfloat16(x - hf);
    lo = *(unsigned short*)&l;
}

__device__ inline float f16u_to_f(unsigned short s) {
    _Float16 h;
    __builtin_memcpy(&h, &s, 2);
    return (float)h;
}

__device__ inline unsigned short f16_bits(float x) {
    _Float16 h = (_Float16)x;
    unsigned short b;
    __builtin_memcpy(&b, &h, 2);
    return b;
}

__device__ inline unsigned int pack_f16x2(float a, float b) {
    return (unsigned int)f16_bits(a) | ((unsigned int)f16_bits(b) << 16);
}

__device__ inline float fast_sigmoid(float x) { return 1.f / (1.f + __expf(-x)); }
__device__ inline float fast_tanh(float x) {
    float e = __expf(2.f * x);
    return 1.f - 2.f / (e + 1.f);
}

// LDS-only barrier: make LDS writes visible and sync the block WITHOUT
// draining vmcnt (global loads/stores stay in flight across the barrier).
__device__ inline void bar_lds_only() {
    asm volatile("s_waitcnt lgkmcnt(0)" ::: "memory");
    __builtin_amdgcn_s_barrier();
    asm volatile("" ::: "memory");
}

// 16-byte async global->LDS copy (per-lane addresses must be wave-linear in
// steps of 16 B on the LDS side — guaranteed by o = tid*8 (+ wave-uniform)).
__device__ inline void stage16(const unsigned short* g, unsigned short* l) {
#if __has_builtin(__builtin_amdgcn_global_load_lds)
    __builtin_amdgcn_global_load_lds(
        (const __attribute__((address_space(1))) unsigned int*)g,
        (__attribute__((address_space(3))) unsigned int*)l, 16, 0, 0);
#else
    *(uint4*)l = *(const uint4*)g;
#endif
}

// ---------------------------------------------------------------------------
// Kernel P: pre-convert wih (both dirs) to the exact f16 LDS tile image.
// ---------------------------------------------------------------------------
__global__ __launch_bounds__(256) void k_prep(
        const float* __restrict__ wih0, const float* __restrict__ wih1,
        unsigned short* __restrict__ Bpre)
{
    int idx = blockIdx.x * 256 + threadIdx.x;       // grid 340*256 == 87040
    if (idx >= 87040) return;
    int q = idx % 136;
    int r = idx / 136;                              // u*320 + gc
    int u2 = r / 320, gc = r % 320;
    const float* wih = u2 ? wih1 : wih0;
    unsigned short v = 0;
    if (q < 100 && gc < 288) v = f16_bits(wih[(size_t)gc * E_ + q]);
    Bpre[idx] = v;
}

// ---------------------------------------------------------------------------
// Kernel A (v6): gi for both directions, one block per 64-row m-tile.
// MFMA orientation: A = emb rows m, B = wih cols gc.  C: lane (c16, quad)
// owns gc = ns*16 + c16 for 4 CONSECUTIVE m (= m0 + w*16 + quad*4 + r2).
// Epilogue writes the m4-grouped layout gi[m/4][gc][m%4] (8-B unit per
// (gc, m4)) as 18 fully-coalesced uint2 stores per lane.
// ---------------------------------------------------------------------------
__global__ __launch_bounds__(256, 4) void k_gi2b(
        const int* __restrict__ tokens, const float* __restrict__ emb,
        const float* __restrict__ bih0, const float* __restrict__ bih1,
        const unsigned short* __restrict__ Bpre,
        unsigned short* __restrict__ g3_0, unsigned short* __restrict__ g3_1,
        int uoff, int ndir)
{
    const int m0 = blockIdx.x * 64;      // 1600 blocks
    const int tid = threadIdx.x;
    const int w = tid >> 6, l = tid & 63;
    const int lr = l & 15, quad = l >> 4;

    __shared__ __align__(16) unsigned short Bt[2][8704];   // 2 x 64 x 136 f16
    __shared__ __align__(16) float biasl[576];

    for (int i = tid; i < 576; i += 256)
        biasl[i] = (i < 288) ? bih0[i] : bih1[i - 288];

    // ---- emb fragments (A operand): lane c16 = m-row, quad = k-octet
    const int trow = tokens[m0 + w * 16 + lr];
    const float* ap = emb + (size_t)trow * E_;
    half8 afr[4];
#pragma unroll
    for (int kk = 0; kk < 4; ++kk) {
        union { unsigned int u[4]; half8 h; } tmp;
#pragma unroll
        for (int pq = 0; pq < 4; ++pq) {
            int k0 = kk * 32 + quad * 8 + pq * 2;
            float2 f = {0.f, 0.f};
            if (k0 + 1 < E_) f = *(const float2*)(ap + k0);   // 8-B aligned
            tmp.u[pq] = pack_f16x2(f.x, f.y);
        }
        afr[kk] = tmp.h;
    }

    f32x4 z4 = {0.f, 0.f, 0.f, 0.f};
    f32x4 acc[18];
#pragma unroll
    for (int i = 0; i < 18; ++i) acc[i] = z4;

    for (int u = uoff; u < uoff + ndir; ++u) {
        const unsigned short* bsrc = Bpre + (size_t)u * 43520;
        __syncthreads();                 // Bt free (prev dir / first use)
        for (int o = tid * 8; o < 8704; o += 2048)
            stage16(bsrc + o, &Bt[0][0] + o);
        __syncthreads();                 // tile 0 resident (+ biasl staged)
#pragma unroll
        for (int nt = 0; nt < 5; ++nt) {
            if (nt < 4) {                // prefetch next tile into other buf
                const unsigned short* s2 = bsrc + (size_t)(nt + 1) * 8704;
                unsigned short* d2 = &Bt[(nt + 1) & 1][0];
                for (int o = tid * 8; o < 8704; o += 2048)
                    stage16(s2 + o, d2 + o);
            }
            const unsigned short* bt = &Bt[nt & 1][0];
#pragma unroll
            for (int kk = 0; kk < 4; ++kk) {
#pragma unroll
                for (int ns = 0; ns < 4; ++ns) {
                    if (nt * 4 + ns < 18) {
                        half8 bv = *(const half8*)(bt + (ns * 16 + lr) * 136 + kk * 32 + quad * 8);
                        // A = emb (M = m), B = wih (N = gc)
                        acc[nt * 4 + ns] =
                            __builtin_amdgcn_mfma_f32_16x16x32_f16(afr[kk], bv, acc[nt * 4 + ns], 0, 0, 0);
                    }
                }
            }
            if (nt < 4) __syncthreads(); // prefetch drained; bufs swap safely
        }
        // ---- epilogue: lane (c16, quad) owns 8-B unit (gc = a*16+c16,
        // m4 = (m0 + w*16 + quad*4)/4); halves within = m%4 = r2 = reg idx.
        unsigned short* gi = u ? g3_1 : g3_0;
        unsigned int* gdw = (unsigned int*)gi;
        const float* bl = biasl + u * 288;
        const size_t m4 = (size_t)((m0 >> 2) + w * 4 + quad);
#pragma unroll
        for (int a = 0; a < 18; ++a) {
            int gc = a * 16 + lr;
            float b = bl[gc];
            unsigned int dlo = pack_f16x2(acc[a][0] + b, acc[a][1] + b);
            unsigned int dhi = pack_f16x2(acc[a][2] + b, acc[a][3] + b);
            *(uint2*)(gdw + m4 * 576 + (size_t)gc * 2) = make_uint2(dlo, dhi);
        }
        if (u + 1 < uoff + ndir) {
#pragma unroll
            for (int i = 0; i < 18; ++i) acc[i] = z4;
        }
    }
}

// ---------------------------------------------------------------------------
// Kernel B (v7): MFMA GRU — k_gru6 with BOTH DIRECTIONS MERGED in one block.
// Round-7: round-6 showed 100 single-stream blocks -> 1 block/CU -> ~2400
// cyc/step of exposed latency (only ~500 cyc is real issue).  The fwd and
// bwd recurrences over the same 16 t-rows are independent chains: one block
// = 768 threads = 12 waves (waves 0-5 fwd j-chunks, 6-11 bwd), each dir has
// its own double-buffered h16, sharing the per-step LDS-only barrier.
// Every SIMD now holds 3 waves from 2 independent dependency chains ->
// dir0's ds_read/MFMA/exp stalls fill with dir1's issue.  Per-dir code path
// is byte-identical to verified k_gru6.  Grid 50 x 768 (primary) or
// 50 x 384 (compact, one dir).
// ---------------------------------------------------------------------------
__global__ __launch_bounds__(768, 1) void k_gru7(
        const unsigned short* __restrict__ gi_f,
        const unsigned short* __restrict__ gi_b,
        const float* __restrict__ whh_f, const float* __restrict__ whh_b,
        const float* __restrict__ bhh_f, const float* __restrict__ bhh_b,
        __hip_bfloat16* __restrict__ hout, int uoff)
{
    const int tg = blockIdx.x;           // 0..49 (16 t-rows each)
    const int tid = threadIdx.x;
    const int ud  = tid / 384;           // 0: first dir, 1: second dir
    const int u   = uoff + ud;           // global dir index
    const int lt  = tid - ud * 384;      // 0..383 within this dir's 6 waves
    const int wv2 = lt >> 6;             // j chunk 0..5
    const int l   = lt & 63;
    const int c16 = l & 15, quad = l >> 4;
    const unsigned short* gi = u ? gi_b : gi_f;
    const float* whh = u ? whh_b : whh_f;
    const float* bhh = u ? bhh_b : bhh_f;

    __shared__ _Float16 h16[2][2][16 * 104];   // [dir][dbuf][t-local x k]

    // ---- W fragments (B operand): lane col = j = wv2*16 + c16, quad = k-octet
    const int j = wv2 * 16 + c16;
    half8 bw[3][3];
    float bias[3];
#pragma unroll
    for (int g = 0; g < 3; ++g) {
        int n = g * 96 + j;
        bias[g] = bhh[n];
#pragma unroll
        for (int kc = 0; kc < 3; ++kc) {
            const float* wp = whh + (size_t)n * 96 + kc * 32 + quad * 8;
            float4 f0 = *(const float4*)wp;
            float4 f1 = *(const float4*)(wp + 4);
            half8 hb;
            hb[0] = (_Float16)f0.x; hb[1] = (_Float16)f0.y;
            hb[2] = (_Float16)f0.z; hb[3] = (_Float16)f0.w;
            hb[4] = (_Float16)f1.x; hb[5] = (_Float16)f1.y;
            hb[6] = (_Float16)f1.z; hb[7] = (_Float16)f1.w;
            bw[g][kc] = hb;
        }
    }
#pragma unroll
    for (int g = 0; g < 3; ++g) {
#pragma unroll
        for (int kc = 0; kc < 3; ++kc)
            asm volatile("" : "+v"(bw[g][kc]));
        asm volatile("" : "+v"(bias[g]));
    }

    for (int idx = tid; idx < 2 * 2 * 16 * 104; idx += blockDim.x)
        (&h16[0][0][0])[idx] = (_Float16)0.f;
    float hst[4] = {0.f, 0.f, 0.f, 0.f};
    __syncthreads();

    // ---- gi addressing (dwords): unit (gc, m4) at m4*576 + gc*2, where
    // m4 = i*200 + tg*4 + quad; per gate g: gc = g*96 + j (+192 dwords).
    const unsigned int* gdw = (const unsigned int*)gi;
    const int i0 = u ? 127 : 0;
    long long base = (long long)(i0 * 200 + tg * 4 + quad) * 576 + (long long)j * 2;
    const long long dstep = (u ? -1LL : 1LL) * 115200;   // 200*576 dwords

    uint2 cR, cZ, cN, nR, nZ, nN;
    cR = *(const uint2*)(gdw + base);
    cZ = *(const uint2*)(gdw + base + 192);
    cN = *(const uint2*)(gdw + base + 384);
    base += dstep;
    nR = *(const uint2*)(gdw + base);
    nZ = *(const uint2*)(gdw + base + 192);
    nN = *(const uint2*)(gdw + base + 384);

    // ---- hout running pointer: (i, t = tg*16+quad*4+r, u*96 + j)
    __hip_bfloat16* hptr = hout + ((size_t)i0 * T_ + tg * 16 + quad * 4) * HC + u * 96 + j;
    const long long hstep = (u ? -1LL : 1LL) * (T_ * HC);

    int cb = 0;

    for (int s = 0; s < 128; ++s) {
        // issue step s+2's gi loads FIRST (2 steps of latency cover; never
        // drained by the LDS-only barrier)
        uint2 fR = nR, fZ = nZ, fN = nN;
        if (s < 126) {
            base += dstep;
            fR = *(const uint2*)(gdw + base);
            fZ = *(const uint2*)(gdw + base + 192);
            fN = *(const uint2*)(gdw + base + 384);
        }

        // h fragments (A operand): lane row = t-local = c16, quad = k-octet
        const _Float16* hb = &h16[ud][cb][0];
        half8 a0 = *(const half8*)(&hb[c16 * 104 + 0  + quad * 8]);
        half8 a1 = *(const half8*)(&hb[c16 * 104 + 32 + quad * 8]);
        half8 a2 = *(const half8*)(&hb[c16 * 104 + 64 + quad * 8]);

        f32x4 acc[3];
#pragma unroll
        for (int g = 0; g < 3; ++g) {
            f32x4 c = {0.f, 0.f, 0.f, 0.f};
            c = __builtin_amdgcn_mfma_f32_16x16x32_f16(a0, bw[g][0], c, 0, 0, 0);
            c = __builtin_amdgcn_mfma_f32_16x16x32_f16(a1, bw[g][1], c, 0, 0, 0);
            c = __builtin_amdgcn_mfma_f32_16x16x32_f16(a2, bw[g][2], c, 0, 0, 0);
            acc[g] = c;
        }

        // gate phase: all 64 lanes, 4 outputs each (t = quad*4+r, j fixed)
        float gr[4], gz[4], gn[4];
        gr[0] = f16u_to_f((unsigned short)(cR.x & 0xffff));
        gr[1] = f16u_to_f((unsigned short)(cR.x >> 16));
        gr[2] = f16u_to_f((unsigned short)(cR.y & 0xffff));
        gr[3] = f16u_to_f((unsigned short)(cR.y >> 16));
        gz[0] = f16u_to_f((unsigned short)(cZ.x & 0xffff));
        gz[1] = f16u_to_f((unsigned short)(cZ.x >> 16));
        gz[2] = f16u_to_f((unsigned short)(cZ.y & 0xffff));
        gz[3] = f16u_to_f((unsigned short)(cZ.y >> 16));
        gn[0] = f16u_to_f((unsigned short)(cN.x & 0xffff));
        gn[1] = f16u_to_f((unsigned short)(cN.x >> 16));
        gn[2] = f16u_to_f((unsigned short)(cN.y & 0xffff));
        gn[3] = f16u_to_f((unsigned short)(cN.y >> 16));

        float hp[4];
#pragma unroll
        for (int r = 0; r < 4; ++r) {
            float hr = acc[0][r] + bias[0];
            float hz = acc[1][r] + bias[1];
            float hn = acc[2][r] + bias[2];
            float rr = fast_sigmoid(gr[r] + hr);
            float zz = fast_sigmoid(gz[r] + hz);
            float nn = fast_tanh(gn[r] + rr * hn);
            hp[r] = (1.f - zz) * nn + zz * hst[r];
            hst[r] = hp[r];
        }

        // h16[ud][cb^1][t-local = quad*4+r][j]  (4 b16 writes)
        _Float16* hw = &h16[ud][cb ^ 1][0];
#pragma unroll
        for (int r = 0; r < 4; ++r)
            hw[(quad * 4 + r) * 104 + j] = (_Float16)hp[r];

        // hout: 4 x 2-B stores at t-stride (fire-and-forget)
#pragma unroll
        for (int r = 0; r < 4; ++r)
            hptr[(size_t)r * HC] = __float2bfloat16(hp[r]);

        bar_lds_only();                  // lgkmcnt(0) + s_barrier, no vmcnt

        cR = nR; cZ = nZ; cN = nN;
        nR = fR; nZ = fZ; nN = fN;
        hptr += hstep;
        cb ^= 1;
    }
}

// ---------------------------------------------------------------------------
// Kernel C1: tt = tanh(h @ A1 + b1)    M=102400, K=192, N=50 (pad 64), MFMA
// ---------------------------------------------------------------------------
__global__ __launch_bounds__(256) void k_att1(
        const __hip_bfloat16* __restrict__ h,
        const float* __restrict__ A1,
        const float* __restrict__ b1,
        __hip_bfloat16* __restrict__ tt)
{
    const int m0 = blockIdx.x * 64;      // 1600 blocks
    const int tid = threadIdx.x;
    __shared__ __align__(16) unsigned short At[64 * 200];
    __shared__ __align__(16) unsigned short Bhi[64 * 200];
    __shared__ __align__(16) unsigned short Blo[64 * 200];
    for (int idx = tid; idx < 64 * 96; idx += 256) {
        int r = idx / 96, p = idx - r * 96;
        unsigned int v = *(const unsigned int*)((const unsigned short*)h + ((size_t)(m0 + r) * HC + 2 * p));
        *(unsigned int*)(&At[r * 200 + 2 * p]) = v;
    }
    for (int idx = tid; idx < 64 * 192; idx += 256) {
        int nn = idx / 192, k = idx - nn * 192;
        unsigned short vh = 0, vl = 0;
        if (nn < 50) split_hilo(A1[k * 50 + nn], vh, vl);   // transpose A1 -> B[n][k]
        Bhi[nn * 200 + k] = vh;
        Blo[nn * 200 + k] = vl;
    }
    __syncthreads();
    const int w = tid >> 6, l = tid & 63;
    const int lr = l & 15, quad = l >> 4;
    f32x4 z4 = {0.f, 0.f, 0.f, 0.f};
    f32x4 acc[4];
#pragma unroll
    for (int i = 0; i < 4; ++i) acc[i] = z4;
#pragma unroll
    for (int kk = 0; kk < 6; ++kk) {
        bf16x8 af = *(const bf16x8*)(&At[(w * 16 + lr) * 200 + kk * 32 + quad * 8]);
#pragma unroll
        for (int ns = 0; ns < 4; ++ns) {
            bf16x8 bh = *(const bf16x8*)(&Bhi[(ns * 16 + lr) * 200 + kk * 32 + quad * 8]);
            bf16x8 bl = *(const bf16x8*)(&Blo[(ns * 16 + lr) * 200 + kk * 32 + quad * 8]);
            acc[ns] = __builtin_amdgcn_mfma_f32_16x16x32_bf16(af, bh, acc[ns], 0, 0, 0);
            acc[ns] = __builtin_amdgcn_mfma_f32_16x16x32_bf16(af, bl, acc[ns], 0, 0, 0);
        }
    }
#pragma unroll
    for (int ns = 0; ns < 4; ++ns) {
        int col = ns * 16 + lr;
        if (col < 50) {
            float bias = b1[col];
#pragma unroll
            for (int r2 = 0; r2 < 4; ++r2) {
                int grow = m0 + w * 16 + quad * 4 + r2;
                tt[(size_t)grow * 50 + col] = __float2bfloat16(fast_tanh(acc[ns][r2] + bias));
            }
        }
    }
}

// ---------------------------------------------------------------------------
// Kernel C2: att = softmax(tt @ A2 + b2, axis=-1)   one row per lane
// ---------------------------------------------------------------------------
__global__ __launch_bounds__(256) void k_att2(
        const __hip_bfloat16* __restrict__ tt,
        const float* __restrict__ A2,
        const float* __restrict__ b2,
        float* __restrict__ att)
{
    __shared__ float A2l[600];
    __shared__ float b2l[12];
    const int tid = threadIdx.x;
    for (int idx = tid; idx < 600; idx += 256) A2l[idx] = A2[idx];
    if (tid < 12) b2l[tid] = b2[tid];
    __syncthreads();
    const int row = blockIdx.x * 256 + tid;    // 400*256 == 102400 exact
    float acc[12];
#pragma unroll
    for (int r = 0; r < 12; ++r) acc[r] = b2l[r];
    const __hip_bfloat16* trow = tt + (size_t)row * 50;
    for (int jj = 0; jj < 50; ++jj) {
        float tv = (float)trow[jj];
#pragma unroll
        for (int r = 0; r < 12; ++r) acc[r] += tv * A2l[jj * 12 + r];
    }
    float mx = acc[0];
#pragma unroll
    for (int r = 1; r < 12; ++r) mx = fmaxf(mx, acc[r]);
    float sm = 0.f;
#pragma unroll
    for (int r = 0; r < 12; ++r) { acc[r] = __expf(acc[r] - mx); sm += acc[r]; }
    float inv = 1.f / sm;
#pragma unroll
    for (int r = 0; r < 12; ++r) att[(size_t)row * 12 + r] = acc[r] * inv;
}

// ---------------------------------------------------------------------------
// Kernel D0: g = att^T att per batch, norms[b] = ||g - I||_F.
// ---------------------------------------------------------------------------
__global__ __launch_bounds__(256) void k_gatt(
        const float* __restrict__ att,
        float* __restrict__ norms)
{
    const int b = blockIdx.x;
    const int tid = threadIdx.x;
    __shared__ __align__(16) float al[9600];
    __shared__ float g_l[144];
    {
        const float4* src = (const float4*)(att + (size_t)b * 9600);
        float4* dst = (float4*)al;
        for (int e = tid; e < 2400; e += 256) dst[e] = src[e];
    }
    __syncthreads();
    if (tid < 144) {
        const int rr = tid / 12, ss = tid - rr * 12;
        float s2 = 0.f;
        for (int t = 0; t < 800; ++t)
            s2 += al[t * 12 + rr] * al[t * 12 + ss];
        g_l[tid] = s2;
    }
    __syncthreads();
    if (tid == 0) {
        float s2 = 0.f;
        for (int idx = 0; idx < 144; ++idx) {
            float v = g_l[idx] - ((idx / 12 == idx % 12) ? 1.f : 0.f);
            s2 += v * v;
        }
        norms[b] = sqrtf(s2);
    }
}

// ---------------------------------------------------------------------------
// Kernel D1 (v3): m[b][r][:] + squash -> v0g, THREE r per block.
// ---------------------------------------------------------------------------
__global__ __launch_bounds__(192) void k_poolm(
        const __hip_bfloat16* __restrict__ h,
        const float* __restrict__ att,
        float* __restrict__ v0g)      // [128][12][192] fp32
{
    const int b = blockIdx.x, r0 = blockIdx.y * 3;
    const int tid = threadIdx.x;
    __shared__ float al[3][800];
    __shared__ float red[3][3];
    __shared__ float sscl[3];

    for (int t = tid; t < 800; t += 192) {
        const float* ap = att + ((size_t)b * 800 + t) * 12 + r0;
        al[0][t] = ap[0];
        al[1][t] = ap[1];
        al[2][t] = ap[2];
    }
    __syncthreads();

    const unsigned short* hp = (const unsigned short*)h + (size_t)b * 800 * 192 + tid;
    float m0 = 0.f, m1 = 0.f, m2 = 0.f;
    for (int t0 = 0; t0 < 800; t0 += 8) {
#pragma unroll
        for (int q = 0; q < 8; ++q) {
            unsigned short hb = hp[(size_t)(t0 + q) * 192];
            float hv = __bfloat162float(*(const __hip_bfloat16*)&hb);
            m0 += hv * al[0][t0 + q];
            m1 += hv * al[1][t0 + q];
            m2 += hv * al[2][t0 + q];
        }
    }
    float s0 = m0 * m0, s1 = m1 * m1, s2 = m2 * m2;
#pragma unroll
    for (int off = 32; off; off >>= 1) {
        s0 += __shfl_down(s0, off);
        s1 += __shfl_down(s1, off);
        s2 += __shfl_down(s2, off);
    }
    if ((tid & 63) == 0) {
        red[0][tid >> 6] = s0; red[1][tid >> 6] = s1; red[2][tid >> 6] = s2;
    }
    __syncthreads();
    if (tid < 3) sscl[tid] = squash_scale(red[tid][0] + red[tid][1] + red[tid][2]);
    __syncthreads();
    float* vp = v0g + ((size_t)b * 12 + r0) * 192 + tid;
    vp[0]   = m0 * sscl[0];
    vp[192] = m1 * sscl[1];
    vp[384] = m2 * sscl[2];
}

// ---------------------------------------------------------------------------
// Kernel D2: u_hat GEMM per r: [128 x 192] @ [192 x 800]. Grid (12, 2, 13).
// ---------------------------------------------------------------------------
__global__ __launch_bounds__(256) void k_uhat(
        const float* __restrict__ v0g,
        const float* __restrict__ Wc,
        float* __restrict__ u_hat)    // [128][12][800] fp32
{
    const int r  = blockIdx.x;           // 0..11
    const int m0 = blockIdx.y * 64;      // 0,64
    const int n0 = blockIdx.z * 64;      // 0..768 (tail tile 32 valid)
    const int tid = threadIdx.x;
    __shared__ __align__(16) unsigned short At[64 * 200];
    __shared__ __align__(16) unsigned short Bt[64 * 200];
    for (int idx = tid; idx < 64 * 96; idx += 256) {
        int row = idx / 96, p = idx - row * 96;
        float2 f = *(const float2*)(v0g + ((size_t)(m0 + row) * 12 + r) * 192 + 2 * p);
        *(unsigned int*)(&At[row * 200 + 2 * p]) = pack_bf16x2(f.x, f.y);
    }
    for (int idx = tid; idx < 192 * 64; idx += 256) {
        int k = idx >> 6, nn = idx & 63;
        unsigned short v = 0;
        if (n0 + nn < 800) v = bf16_bits(Wc[((size_t)r * 192 + k) * 800 + n0 + nn]);
        Bt[nn * 200 + k] = v;
    }
    __syncthreads();
    const int w = tid >> 6, l = tid & 63;
    const int lr = l & 15, quad = l >> 4;
    f32x4 z4 = {0.f, 0.f, 0.f, 0.f};
    f32x4 acc[4];
#pragma unroll
    for (int i = 0; i < 4; ++i) acc[i] = z4;
#pragma unroll
    for (int kk = 0; kk < 6; ++kk) {
        bf16x8 af = *(const bf16x8*)(&At[(w * 16 + lr) * 200 + kk * 32 + quad * 8]);
#pragma unroll
        for (int ns = 0; ns < 4; ++ns) {
            bf16x8 bv = *(const bf16x8*)(&Bt[(ns * 16 + lr) * 200 + kk * 32 + quad * 8]);
            acc[ns] = __builtin_amdgcn_mfma_f32_16x16x32_bf16(af, bv, acc[ns], 0, 0, 0);
        }
    }
#pragma unroll
    for (int ns = 0; ns < 4; ++ns) {
        int cco = n0 + ns * 16 + lr;
        if (cco < 800) {
#pragma unroll
            for (int r2 = 0; r2 < 4; ++r2) {
                int brow = m0 + w * 16 + quad * 4 + r2;
                u_hat[((size_t)brow * 12 + r) * 800 + cco] = acc[ns][r2];
            }
        }
    }
}

// ---------------------------------------------------------------------------
// Kernel D3: dynamic routing per batch (u_hat in LDS), 3 iterations, write v.
// ---------------------------------------------------------------------------
__global__ __launch_bounds__(256) void k_route(
        const float* __restrict__ u_hat,
        float* __restrict__ out)
{
    const int b = blockIdx.x;
    const int tid = threadIdx.x;
    __shared__ __align__(16) float u_l[9600];
    __shared__ float blogl[600];
    __shared__ float c_l[600];
    __shared__ float s_l[800];
    __shared__ float v_l[800];
    __shared__ float scl[64];
    {
        const float4* src = (const float4*)(u_hat + (size_t)b * 9600);
        float4* dst = (float4*)u_l;
        for (int e = tid; e < 2400; e += 256) dst[e] = src[e];
    }
    for (int e = tid; e < 600; e += 256) blogl[e] = 0.f;
    __syncthreads();
    for (int it = 0; it < 3; ++it) {
        if (tid < 12) {
            float mx = -1e30f;
            for (int cc = 0; cc < 50; ++cc) mx = fmaxf(mx, blogl[tid * 50 + cc]);
            float sm = 0.f;
            for (int cc = 0; cc < 50; ++cc) {
                float e2 = __expf(blogl[tid * 50 + cc] - mx);
                c_l[tid * 50 + cc] = e2; sm += e2;
            }
            float inv = 1.f / sm;
            for (int cc = 0; cc < 50; ++cc) c_l[tid * 50 + cc] *= inv;
        }
        __syncthreads();
        for (int e = tid; e < 800; e += 256) {
            int cc = e >> 4;
            float sv = 0.f;
#pragma unroll
            for (int r = 0; r < 12; ++r) sv += c_l[r * 50 + cc] * u_l[r * 800 + e];
            s_l[e] = sv;
        }
        __syncthreads();
        for (int cc = tid; cc < 50; cc += 256) {
            float n2 = 0.f;
#pragma unroll
            for (int o = 0; o < 16; ++o) { float v = s_l[cc * 16 + o]; n2 += v * v; }
            scl[cc] = squash_scale(n2);
        }
        __syncthreads();
        for (int e = tid; e < 800; e += 256) v_l[e] = s_l[e] * scl[e >> 4];
        __syncthreads();
        if (it < 2) {
            for (int e = tid; e < 600; e += 256) {
                int cc = e % 50;
                float dd = 0.f;
#pragma unroll
                for (int o = 0; o < 16; ++o) dd += u_l[e * 16 + o] * v_l[cc * 16 + o];
                blogl[e] += dd;
            }
            __syncthreads();
        }
    }
    for (int e = tid; e < 800; e += 256) out[(size_t)b * 800 + e] = v_l[e];
}

// ---------------------------------------------------------------------------
// Kernel E: att_reg = mean(norms)
// ---------------------------------------------------------------------------
__global__ void k_reg(const float* __restrict__ norms, float* __restrict__ out)
{
    const int l = threadIdx.x;           // 64
    float v = norms[l] + norms[l + 64];
#pragma unroll
    for (int off = 32; off; off >>= 1) v += __shfl_down(v, off);
    if (l == 0) out[OUTV] = v * (1.f / 128.f);
}

// ---------------------------------------------------------------------------
extern "C" void kernel_launch(void* const* d_in, const int* in_sizes, int n_in,
                              void* d_out, int out_size, void* d_ws, size_t ws_size,
                              hipStream_t stream) {
    const int*   tokens = (const int*)d_in[0];
    const float* emb    = (const float*)d_in[1];
    const float* wih_f  = (const float*)d_in[2];
    const float* whh_f  = (const float*)d_in[3];
    const float* bih_f  = (const float*)d_in[4];
    const float* bhh_f  = (const float*)d_in[5];
    const float* wih_b  = (const float*)d_in[6];
    const float* whh_b  = (const float*)d_in[7];
    const float* bih_b  = (const float*)d_in[8];
    const float* bhh_b  = (const float*)d_in[9];
    const float* A1     = (const float*)d_in[10];
    const float* b1     = (const float*)d_in[11];
    const float* A2     = (const float*)d_in[12];
    const float* b2     = (const float*)d_in[13];
    const float* Wc     = (const float*)d_in[14];

    const size_t HB = 39321600;                  // hbuf: 102400*192*2 (bf16)
    const size_t GI = 58982400;                  // gi one dir: 102400*288*2
    const size_t TAIL = 11010560;
    char* ws = (char*)d_ws;
    __hip_bfloat16* hbuf = (__hip_bfloat16*)ws;
    float* out = (float*)d_out;

    if (ws_size >= HB + 2 * GI + TAIL) {
        // ---- primary: both directions resident, single merged GRU ----
        unsigned short* gi_f = (unsigned short*)(ws + HB);
        unsigned short* gi_b = (unsigned short*)(ws + HB + GI);
        char* tail = ws + HB + 2 * GI;
        __hip_bfloat16* tt   = (__hip_bfloat16*)(ws + HB);   // reuses gi_f after GRU
        float*          att  = (float*)(tail);
        float*          nrm  = (float*)(tail + 4915200);
        float*          v0g  = (float*)(tail + 4915712);
        float*          uhat = (float*)(tail + 6095360);
        // Bpre aliases the uhat slot (dead until k_uhat, well after k_gi2b).
        unsigned short* Bpre = (unsigned short*)(tail + 6095360);
        k_prep <<<340, 256, 0, stream>>>(wih_f, wih_b, Bpre);
        k_gi2b <<<1600, 256, 0, stream>>>(tokens, emb, bih_f, bih_b, Bpre, gi_f, gi_b, 0, 2);
        k_gru7<<<50, 768, 0, stream>>>(gi_f, gi_b, whh_f, whh_b, bhh_f, bhh_b, hbuf, 0);
        k_att1 <<<1600, 256, 0, stream>>>(hbuf, A1, b1, tt);
        k_att2 <<<400, 256, 0, stream>>>(tt, A2, b2, att);
        k_gatt <<<128, 256, 0, stream>>>(att, nrm);
        k_poolm<<<dim3(128, 4), 192, 0, stream>>>(hbuf, att, v0g);
        k_uhat <<<dim3(12, 2, 13), 256, 0, stream>>>(v0g, Wc, uhat);
        k_route<<<128, 256, 0, stream>>>(uhat, out);
        k_reg  <<<1, 64, 0, stream>>>(nrm, out);
    } else {
        // ---- compact: one gi buffer, directions sequential ----
        unsigned short* gi1 = (unsigned short*)(ws + HB);
        char* tail = ws + HB + GI;
        __hip_bfloat16* tt   = (__hip_bfloat16*)(ws + HB);
        float*          att  = (float*)(tail);
        float*          nrm  = (float*)(tail + 4915200);
        float*          v0g  = (float*)(tail + 4915712);
        float*          uhat = (float*)(tail + 6095360);
        unsigned short* Bpre = (unsigned short*)(tail + 6095360);
        k_prep <<<340, 256, 0, stream>>>(wih_f, wih_b, Bpre);
        k_gi2b <<<1600, 256, 0, stream>>>(tokens, emb, bih_f, bih_b, Bpre, gi1, gi1, 0, 1);
        k_gru7<<<50, 384, 0, stream>>>(gi1, gi1, whh_f, whh_b, bhh_f, bhh_b, hbuf, 0);
        k_gi2b <<<1600, 256, 0, stream>>>(tokens, emb, bih_f, bih_b, Bpre, gi1, gi1, 1, 1);
        k_gru7<<<50, 384, 0, stream>>>(gi1, gi1, whh_f, whh_b, bhh_f, bhh_b, hbuf, 1);
        k_att1 <<<1600, 256, 0, stream>>>(hbuf, A1, b1, tt);
        k_att2 <<<400, 256, 0, stream>>>(tt, A2, b2, att);
        k_gatt <<<128, 256, 0, stream>>>(att, nrm);
        k_poolm<<<dim3(128, 4), 192, 0, stream>>>(hbuf, att, v0g);
        k_uhat <<<dim3(12, 2, 13), 256, 0, stream>>>(v0g, Wc, uhat);
        k_route<<<128, 256, 0, stream>>>(uhat, out);
        k_reg  <<<1, 64, 0, stream>>>(nrm, out);
    }
}

// Round 9
// 389.296 us; speedup vs baseline: 1.3441x; 1.3441x over previous
//
#include <hip/hip_runtime.h>
#include <hip/hip_bf16.h>
#include <math.h>

typedef short bf16x8 __attribute__((ext_vector_type(8)));
typedef _Float16 half8 __attribute__((ext_vector_type(8)));
typedef float f32x4 __attribute__((ext_vector_type(4)));

#define B_   128
#define T_   800
#define E_   100
#define HC   192       // 2H
#define OUTV 102400    // B*C*O

__device__ inline float squash_scale(float n2) {
    return (n2 / (n2 + 1.f)) * rsqrtf(fmaxf(n2, 1e-30f));
}

__device__ inline unsigned short bf16_bits(float x) {
    __hip_bfloat16 h = __float2bfloat16(x);
    return *(unsigned short*)&h;
}

__device__ inline unsigned int pack_bf16x2(float a, float b) {
    return (unsigned int)bf16_bits(a) | ((unsigned int)bf16_bits(b) << 16);
}

__device__ inline void split_hilo(float x, unsigned short& hi, unsigned short& lo) {
    __hip_bfloat16 h = __float2bfloat16(x);
    float hf = __bfloat162float(h);
    hi = *(unsigned short*)&h;
    __hip_bfloat16 l = __float2bfloat16(x - hf);
    lo = *(unsigned short*)&l;
}

__device__ inline float f16u_to_f(unsigned short s) {
    _Float16 h;
    __builtin_memcpy(&h, &s, 2);
    return (float)h;
}

__device__ inline unsigned short f16_bits(float x) {
    _Float16 h = (_Float16)x;
    unsigned short b;
    __builtin_memcpy(&b, &h, 2);
    return b;
}

__device__ inline unsigned int pack_f16x2(float a, float b) {
    return (unsigned int)f16_bits(a) | ((unsigned int)f16_bits(b) << 16);
}

__device__ inline float fast_sigmoid(float x) { return 1.f / (1.f + __expf(-x)); }
__device__ inline float fast_tanh(float x) {
    float e = __expf(2.f * x);
    return 1.f - 2.f / (e + 1.f);
}

// LDS-only barrier: make LDS writes visible and sync the block WITHOUT
// draining vmcnt (global loads/stores stay in flight across the barrier).
__device__ inline void bar_lds_only() {
    asm volatile("s_waitcnt lgkmcnt(0)" ::: "memory");
    __builtin_amdgcn_s_barrier();
    asm volatile("" ::: "memory");
}

// 16-byte async global->LDS copy (per-lane addresses must be wave-linear in
// steps of 16 B on the LDS side — guaranteed by o = tid*8 (+ wave-uniform)).
__device__ inline void stage16(const unsigned short* g, unsigned short* l) {
#if __has_builtin(__builtin_amdgcn_global_load_lds)
    __builtin_amdgcn_global_load_lds(
        (const __attribute__((address_space(1))) unsigned int*)g,
        (__attribute__((address_space(3))) unsigned int*)l, 16, 0, 0);
#else
    *(uint4*)l = *(const uint4*)g;
#endif
}

// ---------------------------------------------------------------------------
// Kernel P (v2): pre-convert wih (both dirs) to the exact f16 LDS tile image
// AND A1 (transposed) to hi/lo bf16 LDS tile images.
//   Bpre[0 .. 87040)          : wih f16 tiles (2 dirs x 5 x 64 x 136)
//   Bpre[87040 .. 99840)      : A1T hi plane  [64][200]  (nn<50, k<192)
//   Bpre[99840 .. 112640)     : A1T lo plane  [64][200]
// ---------------------------------------------------------------------------
__global__ __launch_bounds__(256) void k_prep(
        const float* __restrict__ wih0, const float* __restrict__ wih1,
        const float* __restrict__ A1,
        unsigned short* __restrict__ Bpre)
{
    int idx = blockIdx.x * 256 + threadIdx.x;       // grid 390*256 == 99840
    if (idx >= 99840) return;
    if (idx < 87040) {
        int q = idx % 136;
        int r = idx / 136;                          // u*320 + gc
        int u2 = r / 320, gc = r % 320;
        const float* wih = u2 ? wih1 : wih0;
        unsigned short v = 0;
        if (q < 100 && gc < 288) v = f16_bits(wih[(size_t)gc * E_ + q]);
        Bpre[idx] = v;
    } else {
        int idx2 = idx - 87040;                     // [0, 12800)
        int nn = idx2 / 200, k = idx2 - nn * 200;
        unsigned short vh = 0, vl = 0;
        if (nn < 50 && k < 192) split_hilo(A1[k * 50 + nn], vh, vl);
        Bpre[87040 + idx2] = vh;
        Bpre[99840 + idx2] = vl;
    }
}

// ---------------------------------------------------------------------------
// Kernel A (v4, round-4 verified @423us total): gi for both directions, one
// block per 64-row m-tile.  gi3 "packet" layout consumed by k_gru4.
// ---------------------------------------------------------------------------
__global__ __launch_bounds__(256, 4) void k_gi2b(
        const int* __restrict__ tokens, const float* __restrict__ emb,
        const float* __restrict__ bih0, const float* __restrict__ bih1,
        const unsigned short* __restrict__ Bpre,
        unsigned short* __restrict__ g3_0, unsigned short* __restrict__ g3_1,
        int uoff, int ndir)
{
    const int m0 = blockIdx.x * 64;      // 1600 blocks
    const int tid = threadIdx.x;
    const int w = tid >> 6, l = tid & 63;
    const int lr = l & 15, quad = l >> 4;

    __shared__ __align__(16) unsigned short Bt[2][8704];   // 2 x 64 x 136 f16
    __shared__ float biasl[576];

    for (int i = tid; i < 576; i += 256)
        biasl[i] = (i < 288) ? bih0[i] : bih1[i - 288];

    // ---- A fragments: emb row for this lane's m-row, f16, K padded to 128
    const int trow = tokens[m0 + w * 16 + lr];
    const float* ap = emb + (size_t)trow * E_;
    half8 afr[4];
#pragma unroll
    for (int kk = 0; kk < 4; ++kk) {
        union { unsigned int u[4]; half8 h; } tmp;
#pragma unroll
        for (int pq = 0; pq < 4; ++pq) {
            int k0 = kk * 32 + quad * 8 + pq * 2;
            float2 f = {0.f, 0.f};
            if (k0 + 1 < E_) f = *(const float2*)(ap + k0);   // 8-B aligned
            tmp.u[pq] = pack_f16x2(f.x, f.y);
        }
        afr[kk] = tmp.h;
    }

    f32x4 z4 = {0.f, 0.f, 0.f, 0.f};
    f32x4 acc[18];
#pragma unroll
    for (int i = 0; i < 18; ++i) acc[i] = z4;

    const int group = w * 2 + (quad >> 1);
    const int lane_g = ((quad & 1) << 4) + lr;

    for (int u = uoff; u < uoff + ndir; ++u) {
        const unsigned short* bsrc = Bpre + (size_t)u * 43520;
        __syncthreads();                 // Bt free (prev dir / first use)
        for (int o = tid * 8; o < 8704; o += 2048)
            stage16(bsrc + o, &Bt[0][0] + o);
        __syncthreads();                 // tile 0 resident (+ biasl staged)
#pragma unroll
        for (int nt = 0; nt < 5; ++nt) {
            if (nt < 4) {                // prefetch next tile into other buf
                const unsigned short* s2 = bsrc + (size_t)(nt + 1) * 8704;
                unsigned short* d2 = &Bt[(nt + 1) & 1][0];
                for (int o = tid * 8; o < 8704; o += 2048)
                    stage16(s2 + o, d2 + o);
            }
            const unsigned short* bt = &Bt[nt & 1][0];
#pragma unroll
            for (int kk = 0; kk < 4; ++kk) {
#pragma unroll
                for (int ns = 0; ns < 4; ++ns) {
                    if (nt * 4 + ns < 18) {
                        half8 bv = *(const half8*)(bt + (ns * 16 + lr) * 136 + kk * 32 + quad * 8);
                        acc[nt * 4 + ns] =
                            __builtin_amdgcn_mfma_f32_16x16x32_f16(afr[kk], bv, acc[nt * 4 + ns], 0, 0, 0);
                    }
                }
            }
            if (nt < 4) __syncthreads(); // prefetch drained; bufs swap safely
        }
        // ---- epilogue: each lane owns 3 complete 48-B gi3 packets ----
        unsigned short* gi3 = u ? g3_1 : g3_0;
        const float* bl = biasl + u * 288;
        const size_t basep = ((size_t)(m0 >> 3) + group) * 2304 + (size_t)lane_g * 24;
#pragma unroll
        for (int wv3 = 0; wv3 < 3; ++wv3) {
            unsigned int uw[12];
#pragma unroll
            for (int pp = 0; pp < 2; ++pp)
#pragma unroll
                for (int gg = 0; gg < 3; ++gg) {
                    int nsg = gg * 6 + wv3 * 2 + pp;
                    float bias = bl[nsg * 16 + lr];
                    int s = pp * 3 + gg;
                    uw[2 * s]     = pack_f16x2(acc[nsg][0] + bias, acc[nsg][1] + bias);
                    uw[2 * s + 1] = pack_f16x2(acc[nsg][2] + bias, acc[nsg][3] + bias);
                }
            uint4* dst = (uint4*)(gi3 + basep + wv3 * 768);
            dst[0] = *(uint4*)&uw[0];
            dst[1] = *(uint4*)&uw[4];
            dst[2] = *(uint4*)&uw[8];
        }
        if (u + 1 < uoff + ndir) {
#pragma unroll
            for (int i = 0; i < 18; ++i) acc[i] = z4;
        }
    }
}

// ---------------------------------------------------------------------------
// Kernel B (round-4 verified @126.9us): MFMA GRU. Grid (200, ndir) x 384.
// h16 double-buffered (one barrier/step), LDS-only barrier (no vmcnt drain),
// 1-step gi3 prefetch, reader-rg shuffle routing.
// ---------------------------------------------------------------------------
__global__ __launch_bounds__(384, 2) void k_gru4(
        const unsigned short* __restrict__ gi3_f,
        const unsigned short* __restrict__ gi3_b,
        const float* __restrict__ whh_f, const float* __restrict__ whh_b,
        const float* __restrict__ bhh_f, const float* __restrict__ bhh_b,
        __hip_bfloat16* __restrict__ hout, int uoff)
{
    const int tc = blockIdx.x;           // 0..199 (4 t-rows each)
    const int u  = blockIdx.y + uoff;    // 0 fwd, 1 bwd
    const int tid = threadIdx.x;
    const int wv2 = tid >> 6;            // col chunk cc = 0..5
    const int l   = tid & 63;
    const int c16 = l & 15, rg = l >> 4; // rg = local t-row (0..3) / k-sub
    const int gblk = tc >> 1, qd = tc & 1;
    const unsigned short* gi3 = u ? gi3_b : gi3_f;
    const float* whh = u ? whh_b : whh_f;
    const float* bhh = u ? bhh_b : bhh_f;

    __shared__ _Float16 h16[2][16 * 104];   // rows 4..15 stay zero (M pad)

    // ---- weights: 3 gates x 3 kchunks for col j = wv2*16 + c16 ----
    const int j = wv2 * 16 + c16;
    half8 bw[3][3];
    float bias[3];
#pragma unroll
    for (int g = 0; g < 3; ++g) {
        int n = g * 96 + j;
        bias[g] = bhh[n];
#pragma unroll
        for (int kc = 0; kc < 3; ++kc) {
            const float* wp = whh + (size_t)n * 96 + kc * 32 + rg * 8;
            float4 f0 = *(const float4*)wp;
            float4 f1 = *(const float4*)(wp + 4);
            half8 hb;
            hb[0] = (_Float16)f0.x; hb[1] = (_Float16)f0.y;
            hb[2] = (_Float16)f0.z; hb[3] = (_Float16)f0.w;
            hb[4] = (_Float16)f1.x; hb[5] = (_Float16)f1.y;
            hb[6] = (_Float16)f1.z; hb[7] = (_Float16)f1.w;
            bw[g][kc] = hb;
        }
    }

    for (int idx = tid; idx < 2 * 16 * 104; idx += 384)
        (&h16[0][0])[idx] = (_Float16)0.f;
    float hst = 0.f;
    __syncthreads();

    // ---- gi3 addressing (dwords). packet = (i*100+gblk)*1152 dwords;
    // within: wv3*384 + lane_g*12 + 6*pp + (rg>>1); gates at stride 2.
    const int wv3 = wv2 >> 1, pp = wv2 & 1;
    const unsigned int* gbase = (const unsigned int*)gi3;
    const int i0 = u ? 127 : 0;
    long long pdw = (long long)(i0 * 100 + gblk) * 1152
                  + wv3 * 384 + (qd * 16 + c16) * 12 + 6 * pp + (rg >> 1);
    const long long dstep = (u ? -1LL : 1LL) * 115200;   // 100*1152 dwords

    unsigned int cur0 = gbase[pdw], cur1 = gbase[pdw + 2], cur2 = gbase[pdw + 4];

    // ---- hout running pointer ----
    const int t = tc * 4 + rg;
    __hip_bfloat16* hptr = hout + ((size_t)i0 * T_ + t) * HC + u * 96 + j;
    const long long hstep = (u ? -1LL : 1LL) * (T_ * HC);

    const int sh = (rg & 1) * 16;
    int cb = 0;

    for (int s = 0; s < 128; ++s) {
        // issue next step's gi3 loads FIRST (consumed next step -> a full
        // step of latency cover; never drained by the LDS-only barrier)
        unsigned int nx0 = cur0, nx1 = cur1, nx2 = cur2;
        if (s < 127) {
            pdw += dstep;
            nx0 = gbase[pdw]; nx1 = gbase[pdw + 2]; nx2 = gbase[pdw + 4];
        }

        const _Float16* hb = &h16[cb][0];
        half8 a0 = *(const half8*)(&hb[c16 * 104 + 0  + rg * 8]);
        half8 a1 = *(const half8*)(&hb[c16 * 104 + 32 + rg * 8]);
        half8 a2 = *(const half8*)(&hb[c16 * 104 + 64 + rg * 8]);

        f32x4 acc[3];
#pragma unroll
        for (int g = 0; g < 3; ++g) {
            f32x4 c = {0.f, 0.f, 0.f, 0.f};
            c = __builtin_amdgcn_mfma_f32_16x16x32_f16(a0, bw[g][0], c, 0, 0, 0);
            c = __builtin_amdgcn_mfma_f32_16x16x32_f16(a1, bw[g][1], c, 0, 0, 0);
            c = __builtin_amdgcn_mfma_f32_16x16x32_f16(a2, bw[g][2], c, 0, 0, 0);
            acc[g] = c;
        }

        // route C[rg][c16] -> this lane: pull all 4 regs from lane c16,
        // then select by the READER's rg. (wave-local; no barrier needed)
        float rt[3];
#pragma unroll
        for (int g = 0; g < 3; ++g) {
            float v0 = __shfl(acc[g][0], c16);
            float v1 = __shfl(acc[g][1], c16);
            float v2 = __shfl(acc[g][2], c16);
            float v3 = __shfl(acc[g][3], c16);
            float lo = (rg & 1) ? v1 : v0;
            float hi = (rg & 1) ? v3 : v2;
            rt[g] = (rg & 2) ? hi : lo;
        }

        float gr = f16u_to_f((unsigned short)(cur0 >> sh));
        float gz = f16u_to_f((unsigned short)(cur1 >> sh));
        float gn = f16u_to_f((unsigned short)(cur2 >> sh));
        float r  = fast_sigmoid(gr + rt[0] + bias[0]);
        float z  = fast_sigmoid(gz + rt[1] + bias[1]);
        float nn = fast_tanh(gn + r * (rt[2] + bias[2]));
        float hp = (1.f - z) * nn + z * hst;
        hst = hp;

        h16[cb ^ 1][rg * 104 + j] = (_Float16)hp;   // write OTHER buffer
        *hptr = __float2bfloat16(hp);

        bar_lds_only();                  // lgkmcnt(0) + s_barrier, no vmcnt

        cur0 = nx0; cur1 = nx1; cur2 = nx2;
        hptr += hstep;
        cb ^= 1;
    }
}

// ---------------------------------------------------------------------------
// Kernel C (fused att1+att2): att = softmax(tanh(h@A1+b1)@A2 + b2, axis=-1).
// 1600 blocks x 256.  A1 hi/lo tiles precomputed by k_prep (no per-block
// split_hilo).  tt lives only in LDS as f32 (no 10MB global round-trip; no
// k_att2 dispatch).  LDS: At(25.6K, overlaid later by ttl/A2l/b2l/scl) +
// Bhi(25.6K) + Blo(25.6K) = 76.8 KB -> 2 blocks/CU (same as old att1).
// ---------------------------------------------------------------------------
__global__ __launch_bounds__(256) void k_attf(
        const __hip_bfloat16* __restrict__ h,
        const unsigned short* __restrict__ Bpre,   // A1 tiles at +87040
        const float* __restrict__ b1,
        const float* __restrict__ A2,
        const float* __restrict__ b2,
        float* __restrict__ att)
{
    const int m0 = blockIdx.x * 64;      // 1600 blocks
    const int tid = threadIdx.x;
    __shared__ __align__(16) unsigned char poolA[64 * 200 * 2];  // At | phase2
    __shared__ __align__(16) unsigned short Bhi[64 * 200];
    __shared__ __align__(16) unsigned short Blo[64 * 200];
    unsigned short* At = (unsigned short*)poolA;
    float* ttl = (float*)poolA;                   // [64][52]  13312 B
    float* A2l = (float*)(poolA + 13312);         // 600 f32    2400 B
    float* b2l = (float*)(poolA + 15712);         // 12 f32       48 B
    float* scl = (float*)(poolA + 15760);         // [64][12]   3072 B

    // stage At (h rows) + A1 hi/lo tiles (plain copies of prep images)
    for (int idx = tid; idx < 64 * 96; idx += 256) {
        int r = idx / 96, p = idx - r * 96;
        unsigned int v = *(const unsigned int*)((const unsigned short*)h + ((size_t)(m0 + r) * HC + 2 * p));
        *(unsigned int*)(&At[r * 200 + 2 * p]) = v;
    }
    {
        const unsigned short* hsrc = Bpre + 87040;
        const unsigned short* lsrc = Bpre + 99840;
        for (int o = tid * 8; o < 12800; o += 2048) {
            stage16(hsrc + o, &Bhi[0] + o);
            stage16(lsrc + o, &Blo[0] + o);
        }
    }
    __syncthreads();
    const int w = tid >> 6, l = tid & 63;
    const int lr = l & 15, quad = l >> 4;
    f32x4 z4 = {0.f, 0.f, 0.f, 0.f};
    f32x4 acc[4];
#pragma unroll
    for (int i = 0; i < 4; ++i) acc[i] = z4;
#pragma unroll
    for (int kk = 0; kk < 6; ++kk) {
        bf16x8 af = *(const bf16x8*)(&At[(w * 16 + lr) * 200 + kk * 32 + quad * 8]);
#pragma unroll
        for (int ns = 0; ns < 4; ++ns) {
            bf16x8 bh = *(const bf16x8*)(&Bhi[(ns * 16 + lr) * 200 + kk * 32 + quad * 8]);
            bf16x8 bl = *(const bf16x8*)(&Blo[(ns * 16 + lr) * 200 + kk * 32 + quad * 8]);
            acc[ns] = __builtin_amdgcn_mfma_f32_16x16x32_bf16(af, bh, acc[ns], 0, 0, 0);
            acc[ns] = __builtin_amdgcn_mfma_f32_16x16x32_bf16(af, bl, acc[ns], 0, 0, 0);
        }
    }
    __syncthreads();                     // At dead -> ttl overlay safe
    // epilogue: tanh -> ttl (f32); stage A2/b2 into the overlay region
#pragma unroll
    for (int ns = 0; ns < 4; ++ns) {
        int col = ns * 16 + lr;
        if (col < 50) {
            float bias = b1[col];
#pragma unroll
            for (int r2 = 0; r2 < 4; ++r2) {
                int rowl = w * 16 + quad * 4 + r2;
                ttl[rowl * 52 + col] = fast_tanh(acc[ns][r2] + bias);
            }
        }
    }
    for (int idx = tid; idx < 600; idx += 256) A2l[idx] = A2[idx];
    if (tid < 12) b2l[tid] = b2[tid];
    __syncthreads();
    // phase 2: sc[row][r] = b2[r] + sum_j ttl[row][j] * A2[j][r]
    {
        const int row = tid & 63, rr = (tid >> 6) * 3;
        float a0 = b2l[rr], a1 = b2l[rr + 1], a2 = b2l[rr + 2];
        for (int jj = 0; jj < 50; ++jj) {
            float tv = ttl[row * 52 + jj];
            const float* ap = &A2l[jj * 12 + rr];
            a0 += tv * ap[0];
            a1 += tv * ap[1];
            a2 += tv * ap[2];
        }
        scl[row * 12 + rr]     = a0;
        scl[row * 12 + rr + 1] = a1;
        scl[row * 12 + rr + 2] = a2;
    }
    __syncthreads();
    // phase 3: per-row softmax + coalesced store
    if (tid < 64) {
        float v[12];
#pragma unroll
        for (int r = 0; r < 12; ++r) v[r] = scl[tid * 12 + r];
        float mx = v[0];
#pragma unroll
        for (int r = 1; r < 12; ++r) mx = fmaxf(mx, v[r]);
        float sm = 0.f;
#pragma unroll
        for (int r = 0; r < 12; ++r) { v[r] = __expf(v[r] - mx); sm += v[r]; }
        float inv = 1.f / sm;
#pragma unroll
        for (int r = 0; r < 12; ++r) v[r] *= inv;
        float* dst = att + (size_t)(m0 + tid) * 12;
        *(float4*)(dst)     = make_float4(v[0], v[1], v[2], v[3]);
        *(float4*)(dst + 4) = make_float4(v[4], v[5], v[6], v[7]);
        *(float4*)(dst + 8) = make_float4(v[8], v[9], v[10], v[11]);
    }
}

// ---------------------------------------------------------------------------
// Kernel D0: g = att^T att per batch, norms[b] = ||g - I||_F.
// ---------------------------------------------------------------------------
__global__ __launch_bounds__(256) void k_gatt(
        const float* __restrict__ att,
        float* __restrict__ norms)
{
    const int b = blockIdx.x;
    const int tid = threadIdx.x;
    __shared__ __align__(16) float al[9600];
    __shared__ float g_l[144];
    {
        const float4* src = (const float4*)(att + (size_t)b * 9600);
        float4* dst = (float4*)al;
        for (int e = tid; e < 2400; e += 256) dst[e] = src[e];
    }
    __syncthreads();
    if (tid < 144) {
        const int rr = tid / 12, ss = tid - rr * 12;
        float s2 = 0.f;
        for (int t = 0; t < 800; ++t)
            s2 += al[t * 12 + rr] * al[t * 12 + ss];
        g_l[tid] = s2;
    }
    __syncthreads();
    if (tid == 0) {
        float s2 = 0.f;
        for (int idx = 0; idx < 144; ++idx) {
            float v = g_l[idx] - ((idx / 12 == idx % 12) ? 1.f : 0.f);
            s2 += v * v;
        }
        norms[b] = sqrtf(s2);
    }
}

// ---------------------------------------------------------------------------
// Kernel D1 (v3): m[b][r][:] + squash -> v0g, THREE r per block.
// ---------------------------------------------------------------------------
__global__ __launch_bounds__(192) void k_poolm(
        const __hip_bfloat16* __restrict__ h,
        const float* __restrict__ att,
        float* __restrict__ v0g)      // [128][12][192] fp32
{
    const int b = blockIdx.x, r0 = blockIdx.y * 3;
    const int tid = threadIdx.x;
    __shared__ float al[3][800];
    __shared__ float red[3][3];
    __shared__ float sscl[3];

    for (int t = tid; t < 800; t += 192) {
        const float* ap = att + ((size_t)b * 800 + t) * 12 + r0;
        al[0][t] = ap[0];
        al[1][t] = ap[1];
        al[2][t] = ap[2];
    }
    __syncthreads();

    const unsigned short* hp = (const unsigned short*)h + (size_t)b * 800 * 192 + tid;
    float m0 = 0.f, m1 = 0.f, m2 = 0.f;
    for (int t0 = 0; t0 < 800; t0 += 8) {
#pragma unroll
        for (int q = 0; q < 8; ++q) {
            unsigned short hb = hp[(size_t)(t0 + q) * 192];
            float hv = __bfloat162float(*(const __hip_bfloat16*)&hb);
            m0 += hv * al[0][t0 + q];
            m1 += hv * al[1][t0 + q];
            m2 += hv * al[2][t0 + q];
        }
    }
    float s0 = m0 * m0, s1 = m1 * m1, s2 = m2 * m2;
#pragma unroll
    for (int off = 32; off; off >>= 1) {
        s0 += __shfl_down(s0, off);
        s1 += __shfl_down(s1, off);
        s2 += __shfl_down(s2, off);
    }
    if ((tid & 63) == 0) {
        red[0][tid >> 6] = s0; red[1][tid >> 6] = s1; red[2][tid >> 6] = s2;
    }
    __syncthreads();
    if (tid < 3) sscl[tid] = squash_scale(red[tid][0] + red[tid][1] + red[tid][2]);
    __syncthreads();
    float* vp = v0g + ((size_t)b * 12 + r0) * 192 + tid;
    vp[0]   = m0 * sscl[0];
    vp[192] = m1 * sscl[1];
    vp[384] = m2 * sscl[2];
}

// ---------------------------------------------------------------------------
// Kernel D2: u_hat GEMM per r: [128 x 192] @ [192 x 800]. Grid (12, 2, 13).
// ---------------------------------------------------------------------------
__global__ __launch_bounds__(256) void k_uhat(
        const float* __restrict__ v0g,
        const float* __restrict__ Wc,
        float* __restrict__ u_hat)    // [128][12][800] fp32
{
    const int r  = blockIdx.x;           // 0..11
    const int m0 = blockIdx.y * 64;      // 0,64
    const int n0 = blockIdx.z * 64;      // 0..768 (tail tile 32 valid)
    const int tid = threadIdx.x;
    __shared__ __align__(16) unsigned short At[64 * 200];
    __shared__ __align__(16) unsigned short Bt[64 * 200];
    for (int idx = tid; idx < 64 * 96; idx += 256) {
        int row = idx / 96, p = idx - row * 96;
        float2 f = *(const float2*)(v0g + ((size_t)(m0 + row) * 12 + r) * 192 + 2 * p);
        *(unsigned int*)(&At[row * 200 + 2 * p]) = pack_bf16x2(f.x, f.y);
    }
    for (int idx = tid; idx < 192 * 64; idx += 256) {
        int k = idx >> 6, nn = idx & 63;
        unsigned short v = 0;
        if (n0 + nn < 800) v = bf16_bits(Wc[((size_t)r * 192 + k) * 800 + n0 + nn]);
        Bt[nn * 200 + k] = v;
    }
    __syncthreads();
    const int w = tid >> 6, l = tid & 63;
    const int lr = l & 15, quad = l >> 4;
    f32x4 z4 = {0.f, 0.f, 0.f, 0.f};
    f32x4 acc[4];
#pragma unroll
    for (int i = 0; i < 4; ++i) acc[i] = z4;
#pragma unroll
    for (int kk = 0; kk < 6; ++kk) {
        bf16x8 af = *(const bf16x8*)(&At[(w * 16 + lr) * 200 + kk * 32 + quad * 8]);
#pragma unroll
        for (int ns = 0; ns < 4; ++ns) {
            bf16x8 bv = *(const bf16x8*)(&Bt[(ns * 16 + lr) * 200 + kk * 32 + quad * 8]);
            acc[ns] = __builtin_amdgcn_mfma_f32_16x16x32_bf16(af, bv, acc[ns], 0, 0, 0);
        }
    }
#pragma unroll
    for (int ns = 0; ns < 4; ++ns) {
        int cco = n0 + ns * 16 + lr;
        if (cco < 800) {
#pragma unroll
            for (int r2 = 0; r2 < 4; ++r2) {
                int brow = m0 + w * 16 + quad * 4 + r2;
                u_hat[((size_t)brow * 12 + r) * 800 + cco] = acc[ns][r2];
            }
        }
    }
}

// ---------------------------------------------------------------------------
// Kernel D3: dynamic routing per batch (u_hat in LDS), 3 iterations, write v.
// ---------------------------------------------------------------------------
__global__ __launch_bounds__(256) void k_route(
        const float* __restrict__ u_hat,
        float* __restrict__ out)
{
    const int b = blockIdx.x;
    const int tid = threadIdx.x;
    __shared__ __align__(16) float u_l[9600];
    __shared__ float blogl[600];
    __shared__ float c_l[600];
    __shared__ float s_l[800];
    __shared__ float v_l[800];
    __shared__ float scl[64];
    {
        const float4* src = (const float4*)(u_hat + (size_t)b * 9600);
        float4* dst = (float4*)u_l;
        for (int e = tid; e < 2400; e += 256) dst[e] = src[e];
    }
    for (int e = tid; e < 600; e += 256) blogl[e] = 0.f;
    __syncthreads();
    for (int it = 0; it < 3; ++it) {
        if (tid < 12) {
            float mx = -1e30f;
            for (int cc = 0; cc < 50; ++cc) mx = fmaxf(mx, blogl[tid * 50 + cc]);
            float sm = 0.f;
            for (int cc = 0; cc < 50; ++cc) {
                float e2 = __expf(blogl[tid * 50 + cc] - mx);
                c_l[tid * 50 + cc] = e2; sm += e2;
            }
            float inv = 1.f / sm;
            for (int cc = 0; cc < 50; ++cc) c_l[tid * 50 + cc] *= inv;
        }
        __syncthreads();
        for (int e = tid; e < 800; e += 256) {
            int cc = e >> 4;
            float sv = 0.f;
#pragma unroll
            for (int r = 0; r < 12; ++r) sv += c_l[r * 50 + cc] * u_l[r * 800 + e];
            s_l[e] = sv;
        }
        __syncthreads();
        for (int cc = tid; cc < 50; cc += 256) {
            float n2 = 0.f;
#pragma unroll
            for (int o = 0; o < 16; ++o) { float v = s_l[cc * 16 + o]; n2 += v * v; }
            scl[cc] = squash_scale(n2);
        }
        __syncthreads();
        for (int e = tid; e < 800; e += 256) v_l[e] = s_l[e] * scl[e >> 4];
        __syncthreads();
        if (it < 2) {
            for (int e = tid; e < 600; e += 256) {
                int cc = e % 50;
                float dd = 0.f;
#pragma unroll
                for (int o = 0; o < 16; ++o) dd += u_l[e * 16 + o] * v_l[cc * 16 + o];
                blogl[e] += dd;
            }
            __syncthreads();
        }
    }
    for (int e = tid; e < 800; e += 256) out[(size_t)b * 800 + e] = v_l[e];
}

// ---------------------------------------------------------------------------
// Kernel E: att_reg = mean(norms)
// ---------------------------------------------------------------------------
__global__ void k_reg(const float* __restrict__ norms, float* __restrict__ out)
{
    const int l = threadIdx.x;           // 64
    float v = norms[l] + norms[l + 64];
#pragma unroll
    for (int off = 32; off; off >>= 1) v += __shfl_down(v, off);
    if (l == 0) out[OUTV] = v * (1.f / 128.f);
}

// ---------------------------------------------------------------------------
extern "C" void kernel_launch(void* const* d_in, const int* in_sizes, int n_in,
                              void* d_out, int out_size, void* d_ws, size_t ws_size,
                              hipStream_t stream) {
    const int*   tokens = (const int*)d_in[0];
    const float* emb    = (const float*)d_in[1];
    const float* wih_f  = (const float*)d_in[2];
    const float* whh_f  = (const float*)d_in[3];
    const float* bih_f  = (const float*)d_in[4];
    const float* bhh_f  = (const float*)d_in[5];
    const float* wih_b  = (const float*)d_in[6];
    const float* whh_b  = (const float*)d_in[7];
    const float* bih_b  = (const float*)d_in[8];
    const float* bhh_b  = (const float*)d_in[9];
    const float* A1     = (const float*)d_in[10];
    const float* b1     = (const float*)d_in[11];
    const float* A2     = (const float*)d_in[12];
    const float* b2     = (const float*)d_in[13];
    const float* Wc     = (const float*)d_in[14];

    const size_t HB = 39321600;                  // hbuf: 102400*192*2 (bf16)
    const size_t GI = 58982400;                  // gi3 one dir: 128*100*2304*2
    const size_t TAIL = 11010560;
    char* ws = (char*)d_ws;
    __hip_bfloat16* hbuf = (__hip_bfloat16*)ws;
    float* out = (float*)d_out;

    if (ws_size >= HB + 2 * GI + TAIL) {
        // ---- primary: both directions resident, single merged GRU ----
        unsigned short* gi_f = (unsigned short*)(ws + HB);
        unsigned short* gi_b = (unsigned short*)(ws + HB + GI);
        char* tail = ws + HB + 2 * GI;
        float*          att  = (float*)(tail);
        float*          nrm  = (float*)(tail + 4915200);
        float*          v0g  = (float*)(tail + 4915712);
        float*          uhat = (float*)(tail + 6095360);
        // Bpre aliases the uhat slot (dead until k_uhat, well after k_attf).
        unsigned short* Bpre = (unsigned short*)(tail + 6095360);
        k_prep <<<390, 256, 0, stream>>>(wih_f, wih_b, A1, Bpre);
        k_gi2b <<<1600, 256, 0, stream>>>(tokens, emb, bih_f, bih_b, Bpre, gi_f, gi_b, 0, 2);
        k_gru4<<<dim3(200, 2), 384, 0, stream>>>(gi_f, gi_b, whh_f, whh_b, bhh_f, bhh_b, hbuf, 0);
        k_attf <<<1600, 256, 0, stream>>>(hbuf, Bpre, b1, A2, b2, att);
        k_gatt <<<128, 256, 0, stream>>>(att, nrm);
        k_poolm<<<dim3(128, 4), 192, 0, stream>>>(hbuf, att, v0g);
        k_uhat <<<dim3(12, 2, 13), 256, 0, stream>>>(v0g, Wc, uhat);
        k_route<<<128, 256, 0, stream>>>(uhat, out);
        k_reg  <<<1, 64, 0, stream>>>(nrm, out);
    } else {
        // ---- compact: one gi3 buffer, directions sequential ----
        unsigned short* gi1 = (unsigned short*)(ws + HB);
        char* tail = ws + HB + GI;
        float*          att  = (float*)(tail);
        float*          nrm  = (float*)(tail + 4915200);
        float*          v0g  = (float*)(tail + 4915712);
        float*          uhat = (float*)(tail + 6095360);
        unsigned short* Bpre = (unsigned short*)(tail + 6095360);
        k_prep <<<390, 256, 0, stream>>>(wih_f, wih_b, A1, Bpre);
        k_gi2b <<<1600, 256, 0, stream>>>(tokens, emb, bih_f, bih_b, Bpre, gi1, gi1, 0, 1);
        k_gru4<<<dim3(200, 1), 384, 0, stream>>>(gi1, gi1, whh_f, whh_b, bhh_f, bhh_b, hbuf, 0);
        k_gi2b <<<1600, 256, 0, stream>>>(tokens, emb, bih_f, bih_b, Bpre, gi1, gi1, 1, 1);
        k_gru4<<<dim3(200, 1), 384, 0, stream>>>(gi1, gi1, whh_f, whh_b, bhh_f, bhh_b, hbuf, 1);
        k_attf <<<1600, 256, 0, stream>>>(hbuf, Bpre, b1, A2, b2, att);
        k_gatt <<<128, 256, 0, stream>>>(att, nrm);
        k_poolm<<<dim3(128, 4), 192, 0, stream>>>(hbuf, att, v0g);
        k_uhat <<<dim3(12, 2, 13), 256, 0, stream>>>(v0g, Wc, uhat);
        k_route<<<128, 256, 0, stream>>>(uhat, out);
        k_reg  <<<1, 64, 0, stream>>>(nrm, out);
    }
}